// Round 11
// baseline (206.207 us; speedup 1.0000x reference)
//
#include <hip/hip_runtime.h>
#include <hip/hip_bf16.h>
#include <math.h>

// Problem constants
constexpr int Bb   = 2;
constexpr int S    = 2048;
constexpr int D    = 1024;
constexpr int H    = 16;
constexpr int Dh   = 64;
constexpr int HALF = 32;            // Dh/2
constexpr int M    = Bb * S;        // 4096 rows in the projection GEMMs
constexpr int K    = 1024;
constexpr int N    = 1024;

typedef __attribute__((ext_vector_type(8))) short short8;   // 8 bf16 (4 VGPRs)
typedef __attribute__((ext_vector_type(4))) float f32x4;    // MFMA C/D

// float -> bf16 bits, round-to-nearest-even
__device__ __forceinline__ unsigned short f2bf(float f) {
    unsigned int u = __float_as_uint(f);
    unsigned int r = (u + 0x7fffu + ((u >> 16) & 1u)) >> 16;
    return (unsigned short)r;
}

// async global->LDS, 16B per lane; LDS dest = wave-uniform base + lane*16
__device__ __forceinline__ void gl_lds16(const unsigned short* g, unsigned short* lds_base) {
    __builtin_amdgcn_global_load_lds(
        (const __attribute__((address_space(1))) unsigned int*)g,
        (__attribute__((address_space(3))) unsigned int*)lds_base, 16, 0, 0);
}

// ---------------------------------------------------------------------------
// Fused prep: blocks [0,256) rope tables (double precision),
// [256,4352) x fp32->bf16, [4352,5376) W fp32 [k][n] -> bf16 W^T [n][k].
// ---------------------------------------------------------------------------
__global__ __launch_bounds__(256) void prep_kernel(
    const float* __restrict__ x,
    const float* W0, const float* W1, const float* W2, const float* W3,
    unsigned short* __restrict__ xb,
    unsigned short* T0, unsigned short* T1, unsigned short* T2, unsigned short* T3,
    float* __restrict__ cosT, float* __restrict__ sinT)
{
    __shared__ float tile[64][65];
    const int bid = blockIdx.x;
    const int tid = threadIdx.x;

    if (bid < 256) {
        int idx = bid * 256 + tid;            // S*HALF = 65536
        int s = idx >> 5;
        int i = idx & 31;
        double freq = exp(-(double)i * (log(10000.0) / 32.0));
        double ang  = (double)s * freq;
        cosT[idx] = (float)cos(ang);
        sinT[idx] = (float)sin(ang);
    } else if (bid < 256 + 4096) {
        size_t i = (size_t)(bid - 256) * 256 + tid;   // over M*K/4
        float4 v = *(const float4*)(x + i * 4);
        ushort4 pk;
        pk.x = f2bf(v.x); pk.y = f2bf(v.y); pk.z = f2bf(v.z); pk.w = f2bf(v.w);
        *(ushort4*)(xb + i * 4) = pk;
    } else {
        int wb = bid - 4352;
        int z  = wb >> 8;
        int rem = wb & 255;
        const float* W = (z == 0) ? W0 : (z == 1) ? W1 : (z == 2) ? W2 : W3;
        unsigned short* T = (z == 0) ? T0 : (z == 1) ? T1 : (z == 2) ? T2 : T3;
        const int bk = (rem >> 4) * 64;   // src row block (k)
        const int bn = (rem & 15) * 64;   // src col block (n)
        const int lr = tid >> 4;          // 0..15
        const int lc = (tid & 15) * 4;    // float4 col

        #pragma unroll
        for (int i = 0; i < 4; ++i) {
            int r = lr + i * 16;
            float4 v = *(const float4*)(W + (size_t)(bk + r) * N + bn + lc);
            tile[r][lc + 0] = v.x; tile[r][lc + 1] = v.y;
            tile[r][lc + 2] = v.z; tile[r][lc + 3] = v.w;
        }
        __syncthreads();
        #pragma unroll
        for (int i = 0; i < 4; ++i) {
            int nr = lr + i * 16;
            ushort4 pk;
            pk.x = f2bf(tile[lc + 0][nr]);
            pk.y = f2bf(tile[lc + 1][nr]);
            pk.z = f2bf(tile[lc + 2][nr]);
            pk.w = f2bf(tile[lc + 3][nr]);
            *(ushort4*)(T + (size_t)(bn + nr) * K + bk + lc) = pk;
        }
    }
}

// ---------------------------------------------------------------------------
// QKV bf16 MFMA GEMM — REVERTED to the r9 winner (59.5 µs measured):
// 128x128 tiles over stacked N=3072, BK=32, single-barrier dbuf K-loop
// unrolled x2, pointer-advance staging, swizzle rot=row>>1 (0 conflicts).
// Grid (24,32)=768 blocks = 3/CU. r10's 64x128/1536-block variant REGRESSED
// (65 µs at 2x occupancy): occupancy is not the binding constraint; the
// structural vmcnt(0) drain at K=1024 is (m131-m141). Do not re-tune.
// Epilogue: z=nbase>>10: z<2 -> bf16 [b][h][s][dh]+RoPE; z=2 -> bf16 V^T.
// ---------------------------------------------------------------------------
__global__ __launch_bounds__(256) void gemm_qkv_kernel(
    const unsigned short* __restrict__ A,
    const unsigned short* __restrict__ BT,
    unsigned short* outQ, unsigned short* outK, unsigned short* outV,
    const float* __restrict__ cosT, const float* __restrict__ sinT)
{
    constexpr int AST = 128 * 32;
    constexpr int BST = 128 * 32;
    __shared__ __align__(16) unsigned short As[2 * AST];
    __shared__ __align__(16) unsigned short Bs[2 * BST];

    const int tid  = threadIdx.x;
    const int wave = tid >> 6;
    const int lane = tid & 63;
    const int col  = lane & 15;
    const int quad = lane >> 4;
    const int wy   = wave >> 1;
    const int wx   = wave & 1;

    const int mbase = blockIdx.y * 128;
    const int nbase = blockIdx.x * 128;

    const int srow   = lane >> 2;
    const int schunk = lane & 3;

    const unsigned short* pA0;
    const unsigned short* pA1;
    {
        int tr0 = wave * 16 + srow;
        int tr1 = 64 + wave * 16 + srow;
        pA0 = A + (size_t)(mbase + tr0) * K + ((schunk + (tr0 >> 1)) & 3) * 8;
        pA1 = A + (size_t)(mbase + tr1) * K + ((schunk + (tr1 >> 1)) & 3) * 8;
    }
    const unsigned short* pB0;
    const unsigned short* pB1;
    {
        int tr0 = wave * 16 + srow;
        int tr1 = 64 + wave * 16 + srow;
        pB0 = BT + (size_t)(nbase + tr0) * K + ((schunk + (tr0 >> 1)) & 3) * 8;
        pB1 = BT + (size_t)(nbase + tr1) * K + ((schunk + (tr1 >> 1)) & 3) * 8;
    }
    unsigned short* dA0 = &As[(wave * 16) * 32];
    unsigned short* dA1 = &As[(64 + wave * 16) * 32];
    unsigned short* dB0 = &Bs[(wave * 16) * 32];
    unsigned short* dB1 = &Bs[(64 + wave * 16) * 32];

    int aoff[4], boff[4];
    #pragma unroll
    for (int mi = 0; mi < 4; ++mi) {
        int r = wy * 64 + mi * 16 + col;
        aoff[mi] = r * 32 + ((quad - (r >> 1)) & 3) * 8;
    }
    #pragma unroll
    for (int ni = 0; ni < 4; ++ni) {
        int r = wx * 64 + ni * 16 + col;
        boff[ni] = r * 32 + ((quad - (r >> 1)) & 3) * 8;
    }

    f32x4 acc[4][4];
    #pragma unroll
    for (int mi = 0; mi < 4; ++mi)
        #pragma unroll
        for (int ni = 0; ni < 4; ++ni) acc[mi][ni] = (f32x4)0.f;

    auto stage = [&](int buf) {
        gl_lds16(pA0, dA0 + buf * AST);  pA0 += 32;
        gl_lds16(pA1, dA1 + buf * AST);  pA1 += 32;
        gl_lds16(pB0, dB0 + buf * BST);  pB0 += 32;
        gl_lds16(pB1, dB1 + buf * BST);  pB1 += 32;
    };
    auto compute = [&](int buf) {
        const unsigned short* Ac = &As[buf * AST];
        const unsigned short* Bc = &Bs[buf * BST];
        short8 af[4], bfr[4];
        #pragma unroll
        for (int mi = 0; mi < 4; ++mi) af[mi] = *(const short8*)&Ac[aoff[mi]];
        #pragma unroll
        for (int ni = 0; ni < 4; ++ni) bfr[ni] = *(const short8*)&Bc[boff[ni]];
        #pragma unroll
        for (int mi = 0; mi < 4; ++mi)
            #pragma unroll
            for (int ni = 0; ni < 4; ++ni)
                acc[mi][ni] = __builtin_amdgcn_mfma_f32_16x16x32_bf16(af[mi], bfr[ni], acc[mi][ni], 0, 0, 0);
    };

    stage(0);
    #pragma unroll 1
    for (int kk = 0; kk < 32; kk += 2) {
        __syncthreads();
        if (kk + 1 < 32) stage(1);
        compute(0);
        __syncthreads();
        if (kk + 2 < 32) stage(0);
        compute(1);
    }

    const int z = nbase >> 10;
    if (z < 2) {
        unsigned short* o = z ? outK : outQ;
        #pragma unroll
        for (int ni = 0; ni < 4; ++ni) {
            int nl = (nbase & 1023) + wx * 64 + ni * 16 + col;
            int h = nl >> 6, dh0 = nl & 63, p = dh0 >> 1;
            bool even = !(dh0 & 1);
            #pragma unroll
            for (int mi = 0; mi < 4; ++mi)
                #pragma unroll
                for (int reg = 0; reg < 4; ++reg) {
                    int m_g = mbase + wy * 64 + mi * 16 + quad * 4 + reg;
                    int b = m_g >> 11, s = m_g & 2047;
                    float v = acc[mi][ni][reg];
                    float part = __shfl_xor(v, 1, 64);
                    float c = cosT[s * HALF + p], sn = sinT[s * HALF + p];
                    float r = even ? (v * c - part * sn) : (v * c + part * sn);
                    o[((size_t)(b * H + h) * S + s) * Dh + dh0] = f2bf(r);
                }
        }
    } else {
        unsigned short* o = outV;
        #pragma unroll
        for (int ni = 0; ni < 4; ++ni) {
            int nl = (nbase & 1023) + wx * 64 + ni * 16 + col;
            int h = nl >> 6, dh0 = nl & 63;
            #pragma unroll
            for (int mi = 0; mi < 4; ++mi) {
                int m0g = mbase + wy * 64 + mi * 16 + quad * 4;
                int b = m0g >> 11, s = m0g & 2047;
                ushort4 pk;
                pk.x = f2bf(acc[mi][ni][0]);
                pk.y = f2bf(acc[mi][ni][1]);
                pk.z = f2bf(acc[mi][ni][2]);
                pk.w = f2bf(acc[mi][ni][3]);
                *(ushort4*)&o[((size_t)(b * H + h) * Dh + dh0) * S + s] = pk;
            }
        }
    }
}

// ---------------------------------------------------------------------------
// Out-projection bf16 MFMA GEMM (r10, kept — saved ~6 µs): 64x64 tiles,
// BK=64 (16 intervals), grid (16,64) = 1024 blocks = 4/CU co-resident.
// ---------------------------------------------------------------------------
__global__ __launch_bounds__(256) void gemm_out_kernel(
    const unsigned short* __restrict__ A,
    const unsigned short* __restrict__ BT,
    float* __restrict__ outO, const float* __restrict__ bias)
{
    constexpr int BK   = 64;
    constexpr int ABUF = 64 * BK;
    constexpr int BBUF = 64 * BK;
    __shared__ __align__(16) unsigned short As[2 * ABUF];
    __shared__ __align__(16) unsigned short Bs[2 * BBUF];

    const int tid  = threadIdx.x;
    const int wave = tid >> 6;
    const int lane = tid & 63;
    const int col  = lane & 15;
    const int quad = lane >> 4;
    const int wy   = wave >> 1;
    const int wx   = wave & 1;

    const int mbase = blockIdx.y * 64;
    const int nbase = blockIdx.x * 64;

    const int srow8 = lane >> 3;
    const int sch8  = lane & 7;

    const unsigned short *pA[2], *pB[2];
    unsigned short *dA[2], *dB[2];
    #pragma unroll
    for (int w = 0; w < 2; ++w) {
        int base = wave * 16 + w * 8;
        int tr = base + srow8;
        pA[w] = A  + (size_t)(mbase + tr) * K + ((sch8 + (tr >> 1)) & 7) * 8;
        pB[w] = BT + (size_t)(nbase + tr) * K + ((sch8 + (tr >> 1)) & 7) * 8;
        dA[w] = &As[base * BK];
        dB[w] = &Bs[base * BK];
    }

    int aoff[2][2], boff[2][2];
    #pragma unroll
    for (int ks = 0; ks < 2; ++ks) {
        #pragma unroll
        for (int mi = 0; mi < 2; ++mi) {
            int r = wy * 32 + mi * 16 + col;
            aoff[ks][mi] = r * BK + (((ks * 4 + quad) - (r >> 1)) & 7) * 8;
        }
        #pragma unroll
        for (int ni = 0; ni < 2; ++ni) {
            int r = wx * 32 + ni * 16 + col;
            boff[ks][ni] = r * BK + (((ks * 4 + quad) - (r >> 1)) & 7) * 8;
        }
    }

    f32x4 acc[2][2];
    #pragma unroll
    for (int mi = 0; mi < 2; ++mi)
        #pragma unroll
        for (int ni = 0; ni < 2; ++ni) acc[mi][ni] = (f32x4)0.f;

    auto stage = [&](int buf) {
        #pragma unroll
        for (int w = 0; w < 2; ++w) { gl_lds16(pA[w], dA[w] + buf * ABUF); pA[w] += BK; }
        #pragma unroll
        for (int w = 0; w < 2; ++w) { gl_lds16(pB[w], dB[w] + buf * BBUF); pB[w] += BK; }
    };
    auto compute = [&](int buf) {
        const unsigned short* Ac = &As[buf * ABUF];
        const unsigned short* Bc = &Bs[buf * BBUF];
        #pragma unroll
        for (int ks = 0; ks < 2; ++ks) {
            short8 af[2], bfr[2];
            #pragma unroll
            for (int mi = 0; mi < 2; ++mi) af[mi] = *(const short8*)&Ac[aoff[ks][mi]];
            #pragma unroll
            for (int ni = 0; ni < 2; ++ni) bfr[ni] = *(const short8*)&Bc[boff[ks][ni]];
            #pragma unroll
            for (int mi = 0; mi < 2; ++mi)
                #pragma unroll
                for (int ni = 0; ni < 2; ++ni)
                    acc[mi][ni] = __builtin_amdgcn_mfma_f32_16x16x32_bf16(af[mi], bfr[ni], acc[mi][ni], 0, 0, 0);
        }
    };

    stage(0);
    #pragma unroll 1
    for (int kk = 0; kk < 16; kk += 2) {
        __syncthreads();
        if (kk + 1 < 16) stage(1);
        compute(0);
        __syncthreads();
        if (kk + 2 < 16) stage(0);
        compute(1);
    }

    #pragma unroll
    for (int ni = 0; ni < 2; ++ni) {
        int n_g = nbase + wx * 32 + ni * 16 + col;
        float bv = bias[n_g];
        #pragma unroll
        for (int mi = 0; mi < 2; ++mi)
            #pragma unroll
            for (int reg = 0; reg < 4; ++reg) {
                int m_g = mbase + wy * 32 + mi * 16 + quad * 4 + reg;
                outO[(size_t)m_g * N + n_g] = acc[mi][ni][reg] + bv;
            }
    }
}

// ---------------------------------------------------------------------------
// MFMA flash attention v6 — MERGED-PAIR SWEEP. Block x holds BOTH q-tiles
// (x, 31-x) in registers and makes ONE K/V sweep t=0..31-x: every tile feeds
// the big q-tile; tiles t<=x also feed the small one. Compute stays balanced
// (33 subtile-visits/block); K/V staging HALVES (17..32 tiles vs 33); barrier
// intervals drop ~19 -> 9..16; K-fragments shared by both q-tiles' QK MFMAs
// (2 independent chains per wave = ILP over the exp/P-relayout chain).
// Two tiles per interval (4 LDS buffers, pair-dbuf). Ps single per wave ->
// PV per q-tile sequential. No-max softmax p = exp(s*0.125 - 8).
// ---------------------------------------------------------------------------
__global__ __launch_bounds__(256) void attn_mfma_kernel(
    const unsigned short* __restrict__ q, const unsigned short* __restrict__ k,
    const unsigned short* __restrict__ vt, unsigned short* __restrict__ ctx)
{
    constexpr int TSZ = 64 * 64;
    __shared__ __align__(16) unsigned short Ks[4 * TSZ];
    __shared__ __align__(16) unsigned short Vs[4 * TSZ];
    __shared__ __align__(16) unsigned short Ps[4][16 * 72];

    const int tid  = threadIdx.x;
    const int wave = tid >> 6;
    const int lane = tid & 63;
    const int col  = lane & 15;
    const int quad = lane >> 4;
    const int l8   = lane >> 3, cp = lane & 7;

    const int bh  = blockIdx.y;
    const int x   = blockIdx.x;       // 0..15
    const int qtb = 31 - x;           // big q-tile (drives the sweep)
    const int qts = x;                // small q-tile
    const unsigned short* qb = q  + (size_t)bh * S * Dh;
    const unsigned short* kb = k  + (size_t)bh * S * Dh;
    const unsigned short* vb = vt + (size_t)bh * Dh * S;
    const int b = bh >> 4, h = bh & 15;

    unsigned short* dk0 = &Ks[(wave * 16 + 0) * 64];
    unsigned short* dk1 = &Ks[(wave * 16 + 8) * 64];
    unsigned short* dv0 = &Vs[(wave * 16 + 0) * 64];
    unsigned short* dv1 = &Vs[(wave * 16 + 8) * 64];

    int foff[2][4];
    #pragma unroll
    for (int ks = 0; ks < 2; ++ks)
        #pragma unroll
        for (int nt = 0; nt < 4; ++nt) {
            int r = nt * 16 + col;
            foff[ks][nt] = r * 64 + (((ks * 4 + quad) - r) & 7) * 8;
        }
    int poffW[4][4];
    #pragma unroll
    for (int nt = 0; nt < 4; ++nt)
        #pragma unroll
        for (int reg = 0; reg < 4; ++reg)
            poffW[nt][reg] = (quad * 4 + reg) * 72 + nt * 16 + col;
    const int poffR0 = col * 72 + quad * 8;

    // staging sources (per lane), advanced 2 tiles per pair-interval
    const unsigned short *pk0, *pk1, *pv0, *pv1, *ok0, *ok1, *ov0, *ov1;
    {
        int r0 = wave * 16 + l8, r1 = r0 + 8;
        pk0 = kb + (size_t)r0 * Dh + ((cp + r0) & 7) * 8;
        pk1 = kb + (size_t)r1 * Dh + ((cp + r1) & 7) * 8;
        pv0 = vb + (size_t)r0 * S + ((cp + r0) & 7) * 8;
        pv1 = vb + (size_t)r1 * S + ((cp + r1) & 7) * 8;
        ok0 = pk0 + 64 * Dh; ok1 = pk1 + 64 * Dh;
        ov0 = pv0 + 64;      ov1 = pv1 + 64;
    }

    // stage pair 0 (tiles 0,1 — qtb >= 16 so both always exist)
    gl_lds16(pk0, dk0); gl_lds16(pk1, dk1);
    gl_lds16(pv0, dv0); gl_lds16(pv1, dv1);
    gl_lds16(ok0, dk0 + TSZ); gl_lds16(ok1, dk1 + TSZ);
    gl_lds16(ov0, dv0 + TSZ); gl_lds16(ov1, dv1 + TSZ);
    pk0 += 128 * Dh; pk1 += 128 * Dh; pv0 += 128; pv1 += 128;
    ok0 += 128 * Dh; ok1 += 128 * Dh; ov0 += 128; ov1 += 128;

    // Q fragments + accumulators for BOTH q-tiles (qi=0 big, qi=1 small)
    short8 qfrag[2][2];
    f32x4 O[2][4];
    float lacc[2][4];
    int wr0[2];
    #pragma unroll
    for (int qi = 0; qi < 2; ++qi) {
        wr0[qi] = (qi ? qts : qtb) * 64 + wave * 16;
        #pragma unroll
        for (int ks = 0; ks < 2; ++ks)
            qfrag[qi][ks] = *(const short8*)(qb + (size_t)(wr0[qi] + col) * Dh + ks * 32 + quad * 8);
        #pragma unroll
        for (int nt = 0; nt < 4; ++nt) O[qi][nt] = (f32x4)0.f;
        #pragma unroll
        for (int r = 0; r < 4; ++r) lacc[qi][r] = 0.f;
    }

    // one dual subtile: K-fragments shared across q-tiles
    auto subtile = [&](const unsigned short* Kc, const unsigned short* Vc,
                       int t, bool both) {
        f32x4 sacc[2][4];
        #pragma unroll
        for (int nt = 0; nt < 4; ++nt) { sacc[0][nt] = (f32x4)0.f; sacc[1][nt] = (f32x4)0.f; }
        #pragma unroll
        for (int ks = 0; ks < 2; ++ks)
            #pragma unroll
            for (int nt = 0; nt < 4; ++nt) {
                short8 kf = *(const short8*)&Kc[foff[ks][nt]];
                sacc[0][nt] = __builtin_amdgcn_mfma_f32_16x16x32_bf16(qfrag[0][ks], kf, sacc[0][nt], 0, 0, 0);
                if (both)
                    sacc[1][nt] = __builtin_amdgcn_mfma_f32_16x16x32_bf16(qfrag[1][ks], kf, sacc[1][nt], 0, 0, 0);
            }
        const int nqi = both ? 2 : 1;
        for (int qi = 0; qi < nqi; ++qi) {
            const int qt_i = qi ? qts : qtb;
            float pb[4][4];
            #pragma unroll
            for (int nt = 0; nt < 4; ++nt) {
                int key_l = nt * 16 + col;
                #pragma unroll
                for (int reg = 0; reg < 4; ++reg) {
                    float e = __expf(fmaf(sacc[qi][nt][reg], 0.125f, -8.0f));
                    if (t == qt_i && key_l > wave * 16 + quad * 4 + reg) e = 0.f;
                    pb[nt][reg] = e;
                }
            }
            #pragma unroll
            for (int reg = 0; reg < 4; ++reg)
                lacc[qi][reg] += (pb[0][reg] + pb[1][reg]) + (pb[2][reg] + pb[3][reg]);
            #pragma unroll
            for (int nt = 0; nt < 4; ++nt)
                #pragma unroll
                for (int reg = 0; reg < 4; ++reg)
                    Ps[wave][poffW[nt][reg]] = f2bf(pb[nt][reg]);
            #pragma unroll
            for (int ks = 0; ks < 2; ++ks) {
                short8 pf = *(const short8*)&Ps[wave][poffR0 + ks * 32];
                #pragma unroll
                for (int nt = 0; nt < 4; ++nt) {
                    short8 vf = *(const short8*)&Vc[foff[ks][nt]];
                    O[qi][nt] = __builtin_amdgcn_mfma_f32_16x16x32_bf16(pf, vf, O[qi][nt], 0, 0, 0);
                }
            }
        }
    };

    const int nint = (qtb + 2) >> 1;      // 9..16 pair-intervals
    for (int i = 0; i < nint; ++i) {
        __syncthreads();                  // drains pair-i staging loads
        const int ta = 2 * i;
        if (ta + 2 <= qtb) {              // prefetch next pair across compute
            const int nb = ((i + 1) & 1) * 2 * TSZ;
            gl_lds16(pk0, dk0 + nb); gl_lds16(pk1, dk1 + nb);
            gl_lds16(pv0, dv0 + nb); gl_lds16(pv1, dv1 + nb);
            if (ta + 3 <= qtb) {
                gl_lds16(ok0, dk0 + nb + TSZ); gl_lds16(ok1, dk1 + nb + TSZ);
                gl_lds16(ov0, dv0 + nb + TSZ); gl_lds16(ov1, dv1 + nb + TSZ);
            }
            pk0 += 128 * Dh; pk1 += 128 * Dh; pv0 += 128; pv1 += 128;
            ok0 += 128 * Dh; ok1 += 128 * Dh; ov0 += 128; ov1 += 128;
        }
        const unsigned short* Kc = &Ks[(i & 1) * 2 * TSZ];
        const unsigned short* Vc = &Vs[(i & 1) * 2 * TSZ];
        subtile(Kc, Vc, ta, ta <= qts);
        if (ta + 1 <= qtb)
            subtile(Kc + TSZ, Vc + TSZ, ta + 1, ta + 1 <= qts);
    }

    // deferred row-sum + store, per q-tile
    #pragma unroll
    for (int qi = 0; qi < 2; ++qi) {
        #pragma unroll
        for (int reg = 0; reg < 4; ++reg) {
            float s = lacc[qi][reg];
            #pragma unroll
            for (int off = 1; off <= 8; off <<= 1)
                s += __shfl_xor(s, off, 64);
            float inv = 1.0f / s;
            int rg = wr0[qi] + quad * 4 + reg;
            unsigned short* dst = ctx + ((size_t)b * S + rg) * 1024 + h * 64 + col;
            #pragma unroll
            for (int nt = 0; nt < 4; ++nt)
                dst[nt * 16] = f2bf(O[qi][nt][reg] * inv);
        }
    }
}

// ---------------------------------------------------------------------------
extern "C" void kernel_launch(void* const* d_in, const int* in_sizes, int n_in,
                              void* d_out, int out_size, void* d_ws, size_t ws_size,
                              hipStream_t stream) {
    const float* x  = (const float*)d_in[0];
    const float* Wq = (const float*)d_in[1];
    const float* Wk = (const float*)d_in[2];
    const float* Wv = (const float*)d_in[3];
    const float* Wo = (const float*)d_in[4];
    const float* bo = (const float*)d_in[5];
    float* out = (float*)d_out;

    const size_t MK  = (size_t)M * K;        // 4M
    const size_t NK  = (size_t)N * K;        // 1M
    const size_t QKV = (size_t)Bb * H * S * Dh;

    unsigned short* xb   = (unsigned short*)d_ws;
    unsigned short* WqT  = xb  + MK;         // WqT/WkT/WvT contiguous = stacked [3072][1024]
    unsigned short* WkT  = WqT + NK;
    unsigned short* WvT  = WkT + NK;
    unsigned short* WoT  = WvT + NK;
    unsigned short* qbuf = WoT + NK;
    unsigned short* kbuf = qbuf + QKV;
    unsigned short* vtb  = kbuf + QKV;
    unsigned short* ctxb = vtb  + QKV;
    float* cosT = (float*)(ctxb + QKV);
    float* sinT = cosT + (size_t)S * HALF;

    // fused prep: rope tables + x->bf16 + 4x W transpose->bf16
    prep_kernel<<<5376, 256, 0, stream>>>(x, Wq, Wk, Wv, Wo,
                                          xb, WqT, WkT, WvT, WoT, cosT, sinT);

    // fused QKV projections as one stacked-N GEMM (+RoPE, +V transpose)
    gemm_qkv_kernel<<<dim3(24, 32), 256, 0, stream>>>(
        xb, WqT, qbuf, kbuf, vtb, cosT, sinT);

    // merged-pair sweep attention
    attn_mfma_kernel<<<dim3(16, Bb * H), 256, 0, stream>>>(qbuf, kbuf, vtb, ctxb);

    // output projection: 64x64 tiles, BK=64, 1024 blocks = 4/CU
    gemm_out_kernel<<<dim3(16, 64), 256, 0, stream>>>(ctxb, WoT, out, bo);
}